// Round 1
// baseline (615.810 us; speedup 1.0000x reference)
//
#include <hip/hip_runtime.h>

#define E_ 8
#define N_ 4096
#define D_ 1024
#define DFF_ 2048
#define NE_ 65536

typedef __attribute__((ext_vector_type(8))) short short8;
typedef __attribute__((ext_vector_type(4))) float f32x4;

__device__ __forceinline__ unsigned short f2bf(float f) {
  unsigned u = __float_as_uint(f);
  u += 0x7fffu + ((u >> 16) & 1u);   // round-to-nearest-even
  return (unsigned short)(u >> 16);
}
__device__ __forceinline__ float bf2f(unsigned short h) {
  return __uint_as_float(((unsigned)h) << 16);
}

// ---------------- conversion kernels ----------------

__global__ __launch_bounds__(256) void cvt_f32_bf16_vec(
    const float* __restrict__ in, unsigned short* __restrict__ out, int n4) {
  int i = blockIdx.x * 256 + threadIdx.x;
  if (i >= n4) return;
  float4 v = ((const float4*)in)[i];
  ushort4 o;
  o.x = f2bf(v.x); o.y = f2bf(v.y); o.z = f2bf(v.z); o.w = f2bf(v.w);
  ((ushort4*)out)[i] = o;
}

// in: [E][R][C] f32  ->  out: [E][C][R] bf16
__global__ __launch_bounds__(256) void transpose_cvt(
    const float* __restrict__ in, unsigned short* __restrict__ out, int R, int C) {
  __shared__ float tile[32][33];
  const int e = blockIdx.z;
  const float* ine = in + (size_t)e * R * C;
  unsigned short* oute = out + (size_t)e * R * C;
  const int c0 = blockIdx.x * 32, r0 = blockIdx.y * 32;
  const int tx = threadIdx.x & 31, ty = threadIdx.x >> 5;
#pragma unroll
  for (int i = 0; i < 32; i += 8)
    tile[ty + i][tx] = ine[(size_t)(r0 + ty + i) * C + (c0 + tx)];
  __syncthreads();
#pragma unroll
  for (int i = 0; i < 32; i += 8)
    oute[(size_t)(c0 + ty + i) * R + (r0 + tx)] = f2bf(tile[tx][ty + i]);
}

// ---------------- CSR build ----------------

__global__ __launch_bounds__(256) void zero_i32(int* __restrict__ p, int n) {
  int i = blockIdx.x * 256 + threadIdx.x;
  if (i < n) p[i] = 0;
}

__global__ __launch_bounds__(256) void hist_dst(
    const int* __restrict__ ei, int* __restrict__ cnt, int ne) {
  int i = blockIdx.x * 256 + threadIdx.x;
  if (i < ne) atomicAdd(&cnt[ei[ne + i]], 1);
}

// single block, 1024 threads, n = 4096 (4 per thread)
__global__ __launch_bounds__(1024) void scan4096(
    const int* __restrict__ cnt, int* __restrict__ rowptr, int* __restrict__ cursor) {
  __shared__ int tmp[1024];
  const int tid = threadIdx.x;
  const int b = tid * 4;
  int c0 = cnt[b + 0], c1 = cnt[b + 1], c2 = cnt[b + 2], c3 = cnt[b + 3];
  int tot = c0 + c1 + c2 + c3;
  tmp[tid] = tot;
  __syncthreads();
  int val = tot;
  for (int off = 1; off < 1024; off <<= 1) {
    int v = 0;
    if (tid >= off) v = tmp[tid - off];
    __syncthreads();
    val += v;
    tmp[tid] = val;
    __syncthreads();
  }
  const int excl = val - tot;
  rowptr[b + 0] = excl;
  rowptr[b + 1] = excl + c0;
  rowptr[b + 2] = excl + c0 + c1;
  rowptr[b + 3] = excl + c0 + c1 + c2;
  cursor[b + 0] = excl;
  cursor[b + 1] = excl + c0;
  cursor[b + 2] = excl + c0 + c1;
  cursor[b + 3] = excl + c0 + c1 + c2;
  if (tid == 1023) rowptr[N_] = val;
}

__global__ __launch_bounds__(256) void fill_csr(
    const int* __restrict__ ei, int* __restrict__ cursor, int* __restrict__ csr, int ne) {
  int i = blockIdx.x * 256 + threadIdx.x;
  if (i < ne) {
    int s = ei[i];
    int d = ei[ne + i];
    int pos = atomicAdd(&cursor[d], 1);
    csr[pos] = s;
  }
}

// ---------------- bf16 MFMA GEMM: C = A * BT^T ----------------
// A  : [M][K]  bf16 row-major (per-expert stride M*K)
// BT : [Nm][K] bf16 row-major (B transposed)
// C  : [M][Nm] bf16 (optionally relu)
// tiles: BM=BN=128, BK=32; 4 waves in 2x2, each 64x64 = 4x4 frags of 16x16x32

template <bool RELU>
__global__ __launch_bounds__(256) void gemm_bf16(
    const unsigned short* __restrict__ A, const unsigned short* __restrict__ BT,
    unsigned short* __restrict__ Cb, int M, int Nm, int K) {
  __shared__ unsigned short lds[8192];  // 8KB A tile + 8KB BT tile
  char* ldsb = (char*)lds;

  const int e = blockIdx.z;
  const unsigned short* Ae = A + (size_t)e * M * K;
  const unsigned short* Be = BT + (size_t)e * Nm * K;
  unsigned short* Ce = Cb + (size_t)e * M * Nm;

  const int m0 = blockIdx.y * 128;
  const int n0 = blockIdx.x * 128;
  const int tid = threadIdx.x;
  const int lane = tid & 63;
  const int wid = tid >> 6;
  const int wr = wid >> 1, wc = wid & 1;

  // staging slots: linear LDS slot m (16B chunks) holds global chunk
  // (row r = m>>2, colchunk c = (m&3) ^ ((r>>1)&3))  -- XOR swizzle
  int sr[2], sc[2];
#pragma unroll
  for (int i = 0; i < 2; ++i) {
    int m = tid + i * 256;
    int r = m >> 2, cc = m & 3;
    sr[i] = r;
    sc[i] = cc ^ ((r >> 1) & 3);
  }

  // fragment read byte-offsets (swizzled to match)
  int a_off[4], b_off[4];
#pragma unroll
  for (int f = 0; f < 4; ++f) {
    int r = wr * 64 + f * 16 + (lane & 15);
    int c = lane >> 4;
    a_off[f] = r * 64 + ((c ^ ((r >> 1) & 3)) << 4);
    int nn = wc * 64 + f * 16 + (lane & 15);
    b_off[f] = 8192 + nn * 64 + ((c ^ ((nn >> 1) & 3)) << 4);
  }

  f32x4 acc[4][4];
#pragma unroll
  for (int i = 0; i < 4; ++i)
#pragma unroll
    for (int j = 0; j < 4; ++j) acc[i][j] = (f32x4){0.f, 0.f, 0.f, 0.f};

  const int nkt = K >> 5;
  for (int kt = 0; kt < nkt; ++kt) {
    if (kt) __syncthreads();  // prior tile's ds_reads done before overwrite
#pragma unroll
    for (int i = 0; i < 2; ++i) {
      const unsigned short* ga = Ae + (size_t)(m0 + sr[i]) * K + (kt << 5) + sc[i] * 8;
      __builtin_amdgcn_global_load_lds(
          (const __attribute__((address_space(1))) void*)ga,
          (__attribute__((address_space(3))) void*)(ldsb + i * 4096 + wid * 1024),
          16, 0, 0);
      const unsigned short* gb = Be + (size_t)(n0 + sr[i]) * K + (kt << 5) + sc[i] * 8;
      __builtin_amdgcn_global_load_lds(
          (const __attribute__((address_space(1))) void*)gb,
          (__attribute__((address_space(3))) void*)(ldsb + 8192 + i * 4096 + wid * 1024),
          16, 0, 0);
    }
    __syncthreads();  // drains vmcnt(0) -> staged data visible to all waves

    short8 af[4], bfr[4];
#pragma unroll
    for (int f = 0; f < 4; ++f) {
      af[f] = *(const short8*)(ldsb + a_off[f]);
      bfr[f] = *(const short8*)(ldsb + b_off[f]);
    }
#pragma unroll
    for (int i = 0; i < 4; ++i)
#pragma unroll
      for (int j = 0; j < 4; ++j)
        acc[i][j] = __builtin_amdgcn_mfma_f32_16x16x32_bf16(af[i], bfr[j], acc[i][j], 0, 0, 0);
  }

  // epilogue: C/D layout col = lane&15, row = (lane>>4)*4 + reg
  const int row0 = m0 + wr * 64 + ((lane >> 4) << 2);
  const int col0 = n0 + wc * 64 + (lane & 15);
#pragma unroll
  for (int i = 0; i < 4; ++i)
#pragma unroll
    for (int j = 0; j < 4; ++j)
#pragma unroll
      for (int r = 0; r < 4; ++r) {
        float v = acc[i][j][r];
        if (RELU) v = fmaxf(v, 0.f);
        Ce[(size_t)(row0 + i * 16 + r) * Nm + (col0 + j * 16)] = f2bf(v);
      }
}

// ---------------- gather: out[e,dst,:] = sum over in-edges of y[e,src,:] ----------------

__global__ __launch_bounds__(256) void gather_sum(
    const unsigned short* __restrict__ y, const int* __restrict__ rowptr,
    const int* __restrict__ csr, float* __restrict__ out) {
  const int dst = blockIdx.x;
  const int e = blockIdx.y;
  const unsigned short* ye = y + (size_t)e * N_ * D_;
  float* oute = out + (size_t)e * N_ * D_ + (size_t)dst * D_;
  const int t = threadIdx.x;  // 256 threads x 4 elems = 1024 = D
  const int beg = rowptr[dst], end = rowptr[dst + 1];
  float a0 = 0.f, a1 = 0.f, a2 = 0.f, a3 = 0.f;
  for (int i = beg; i < end; ++i) {
    const int s = csr[i];
    ushort4 v = ((const ushort4*)(ye + (size_t)s * D_))[t];
    a0 += bf2f(v.x);
    a1 += bf2f(v.y);
    a2 += bf2f(v.z);
    a3 += bf2f(v.w);
  }
  float4 o;
  o.x = a0; o.y = a1; o.z = a2; o.w = a3;
  ((float4*)oute)[t] = o;
}

// ---------------- launch ----------------

extern "C" void kernel_launch(void* const* d_in, const int* in_sizes, int n_in,
                              void* d_out, int out_size, void* d_ws, size_t ws_size,
                              hipStream_t stream) {
  (void)in_sizes; (void)n_in; (void)out_size; (void)ws_size;
  const float* x = (const float*)d_in[0];
  const float* W1 = (const float*)d_in[1];
  const float* W2 = (const float*)d_in[2];
  const int* ei = (const int*)d_in[3];
  float* out = (float*)d_out;

  char* p = (char*)d_ws;
  auto alloc = [&](size_t b) {
    char* r = p;
    p += (b + 255) & ~(size_t)255;
    return r;
  };
  unsigned short* xbf = (unsigned short*)alloc((size_t)E_ * N_ * D_ * 2);    // 64 MiB
  unsigned short* w1t = (unsigned short*)alloc((size_t)E_ * D_ * DFF_ * 2);  // 32 MiB
  unsigned short* w2t = (unsigned short*)alloc((size_t)E_ * DFF_ * D_ * 2);  // 32 MiB
  unsigned short* h = (unsigned short*)alloc((size_t)E_ * N_ * DFF_ * 2);    // 128 MiB
  unsigned short* y = (unsigned short*)alloc((size_t)E_ * N_ * D_ * 2);      // 64 MiB
  int* cnt = (int*)alloc((size_t)N_ * 4);
  int* rowptr = (int*)alloc((size_t)(N_ + 1) * 4);
  int* cursor = (int*)alloc((size_t)N_ * 4);
  int* csr = (int*)alloc((size_t)NE_ * 4);

  // input conversion
  cvt_f32_bf16_vec<<<(E_ * N_ * D_ / 4 + 255) / 256, 256, 0, stream>>>(x, xbf, E_ * N_ * D_ / 4);
  // W1 [E][D][DFF] -> w1t [E][DFF][D]
  transpose_cvt<<<dim3(DFF_ / 32, D_ / 32, E_), 256, 0, stream>>>(W1, w1t, D_, DFF_);
  // W2 [E][DFF][D] -> w2t [E][D][DFF]
  transpose_cvt<<<dim3(D_ / 32, DFF_ / 32, E_), 256, 0, stream>>>(W2, w2t, DFF_, D_);

  // CSR build (edge graph shared across experts)
  zero_i32<<<(N_ + 255) / 256, 256, 0, stream>>>(cnt, N_);
  hist_dst<<<NE_ / 256, 256, 0, stream>>>(ei, cnt, NE_);
  scan4096<<<1, 1024, 0, stream>>>(cnt, rowptr, cursor);
  fill_csr<<<NE_ / 256, 256, 0, stream>>>(ei, cursor, csr, NE_);

  // h = relu(x @ W1)   [E][N][DFF] bf16
  gemm_bf16<true><<<dim3(DFF_ / 128, N_ / 128, E_), 256, 0, stream>>>(xbf, w1t, h, N_, DFF_, D_);
  // y = h @ W2         [E][N][D] bf16
  gemm_bf16<false><<<dim3(D_ / 128, N_ / 128, E_), 256, 0, stream>>>(h, w2t, y, N_, D_, DFF_);

  // out = A @ y  (CSR gather, f32 accumulate)
  gather_sum<<<dim3(N_, E_), 256, 0, stream>>>(y, rowptr, csr, out);
}

// Round 2
// 484.266 us; speedup vs baseline: 1.2716x; 1.2716x over previous
//
#include <hip/hip_runtime.h>

#define E_ 8
#define N_ 4096
#define D_ 1024
#define DFF_ 2048
#define NE_ 65536

typedef __attribute__((ext_vector_type(8))) short short8;
typedef __attribute__((ext_vector_type(4))) float f32x4;

__device__ __forceinline__ unsigned short f2bf(float f) {
  unsigned u = __float_as_uint(f);
  u += 0x7fffu + ((u >> 16) & 1u);   // round-to-nearest-even
  return (unsigned short)(u >> 16);
}
__device__ __forceinline__ float bf2f(unsigned short h) {
  return __uint_as_float(((unsigned)h) << 16);
}

// ---------------- conversion kernels ----------------

__global__ __launch_bounds__(256) void cvt_f32_bf16_vec(
    const float* __restrict__ in, unsigned short* __restrict__ out, int n4) {
  int i = blockIdx.x * 256 + threadIdx.x;
  if (i >= n4) return;
  float4 v = ((const float4*)in)[i];
  ushort4 o;
  o.x = f2bf(v.x); o.y = f2bf(v.y); o.z = f2bf(v.z); o.w = f2bf(v.w);
  ((ushort4*)out)[i] = o;
}

// in: [E][R][C] f32  ->  out: [E][C][R] bf16
__global__ __launch_bounds__(256) void transpose_cvt(
    const float* __restrict__ in, unsigned short* __restrict__ out, int R, int C) {
  __shared__ float tile[32][33];
  const int e = blockIdx.z;
  const float* ine = in + (size_t)e * R * C;
  unsigned short* oute = out + (size_t)e * R * C;
  const int c0 = blockIdx.x * 32, r0 = blockIdx.y * 32;
  const int tx = threadIdx.x & 31, ty = threadIdx.x >> 5;
#pragma unroll
  for (int i = 0; i < 32; i += 8)
    tile[ty + i][tx] = ine[(size_t)(r0 + ty + i) * C + (c0 + tx)];
  __syncthreads();
#pragma unroll
  for (int i = 0; i < 32; i += 8)
    oute[(size_t)(c0 + ty + i) * R + (r0 + tx)] = f2bf(tile[tx][ty + i]);
}

// ---------------- CSR build ----------------

__global__ __launch_bounds__(256) void zero_i32(int* __restrict__ p, int n) {
  int i = blockIdx.x * 256 + threadIdx.x;
  if (i < n) p[i] = 0;
}

__global__ __launch_bounds__(256) void hist_dst(
    const int* __restrict__ ei, int* __restrict__ cnt, int ne) {
  int i = blockIdx.x * 256 + threadIdx.x;
  if (i < ne) atomicAdd(&cnt[ei[ne + i]], 1);
}

__global__ __launch_bounds__(1024) void scan4096(
    const int* __restrict__ cnt, int* __restrict__ rowptr, int* __restrict__ cursor) {
  __shared__ int tmp[1024];
  const int tid = threadIdx.x;
  const int b = tid * 4;
  int c0 = cnt[b + 0], c1 = cnt[b + 1], c2 = cnt[b + 2], c3 = cnt[b + 3];
  int tot = c0 + c1 + c2 + c3;
  tmp[tid] = tot;
  __syncthreads();
  int val = tot;
  for (int off = 1; off < 1024; off <<= 1) {
    int v = 0;
    if (tid >= off) v = tmp[tid - off];
    __syncthreads();
    val += v;
    tmp[tid] = val;
    __syncthreads();
  }
  const int excl = val - tot;
  rowptr[b + 0] = excl;
  rowptr[b + 1] = excl + c0;
  rowptr[b + 2] = excl + c0 + c1;
  rowptr[b + 3] = excl + c0 + c1 + c2;
  cursor[b + 0] = excl;
  cursor[b + 1] = excl + c0;
  cursor[b + 2] = excl + c0 + c1;
  cursor[b + 3] = excl + c0 + c1 + c2;
  if (tid == 1023) rowptr[N_] = val;
}

__global__ __launch_bounds__(256) void fill_csr(
    const int* __restrict__ ei, int* __restrict__ cursor, int* __restrict__ csr, int ne) {
  int i = blockIdx.x * 256 + threadIdx.x;
  if (i < ne) {
    int s = ei[i];
    int d = ei[ne + i];
    int pos = atomicAdd(&cursor[d], 1);
    csr[pos] = s;
  }
}

// ---------------- 256x256 8-phase bf16 MFMA GEMM: C = A * BT^T ----------------
// A : [M][K] bf16 row-major, BT : [Nm][K] bf16 row-major (per-expert strides)
// 512 threads = 8 waves (2M x 4N); per-wave 128x64 out = 8x4 frags of 16x16.
// LDS: 2 buf x 2 halves x [128 rows][64 cols] bf16 per operand = 128 KiB.
// Chunk swizzle: slot = r*8 + (c ^ (r&7)) -> conflict-free ds_read_b128.

#define BAR() asm volatile("s_barrier" ::: "memory")
#define WAIT_LGKM0() asm volatile("s_waitcnt lgkmcnt(0)" ::: "memory")
#define WAIT_VM(n) asm volatile("s_waitcnt vmcnt(" #n ")" ::: "memory")

#define ALDS(buf, h) ((((buf) << 1) | (h)) * 16384)
#define BLDS(buf, h) (65536 + (((buf) << 1) | (h)) * 16384)

template <bool RELU>
__global__ __launch_bounds__(512, 1) void gemm256(
    const unsigned short* __restrict__ A, const unsigned short* __restrict__ BT,
    unsigned short* __restrict__ Cb, int M, int Nm, int K, int nbx, int nbxy) {
  __shared__ char lds[131072];

  // XCD-aware swizzle: nwg = nbxy * 8, each XCD gets one expert's blocks
  const int orig = blockIdx.x;
  const int sw = (orig & 7) * nbxy + (orig >> 3);
  const int e = sw / nbxy;
  const int rem = sw - e * nbxy;
  const int by = rem / nbx;
  const int bx = rem - by * nbx;
  const int m0 = by * 256, n0 = bx * 256;

  const int tid = threadIdx.x;
  const int lane = tid & 63;
  const int wid = tid >> 6;
  const int wm = wid >> 2;   // 0..1
  const int wn = wid & 3;    // 0..3
  const int lo = lane & 15, hi = lane >> 4;

  const unsigned short* Ae = A + (size_t)e * M * K;
  const unsigned short* Be = BT + (size_t)e * Nm * K;
  unsigned short* Ce = Cb + (size_t)e * M * Nm;

  const unsigned short* Abase = Ae + (size_t)m0 * K;
  const unsigned short* Bbase = Be + (size_t)n0 * K;
  const size_t khalf = (size_t)128 * K;

  // staging source offsets (slot s holds global chunk r=s>>3, c=(s&7)^(r&7))
  const int s1 = tid + 512;
  const int r0s = tid >> 3, c0s = (tid & 7) ^ (r0s & 7);
  const int r1s = s1 >> 3, c1s = (s1 & 7) ^ (r1s & 7);
  const int eo0 = r0s * K + c0s * 8;
  const int eo1 = r1s * K + c1s * 8;

#define STAGE(gbase_, ldsoff_)                                                             \
  do {                                                                                     \
    __builtin_amdgcn_global_load_lds(                                                      \
        (const __attribute__((address_space(1))) void*)((gbase_) + eo0),                   \
        (__attribute__((address_space(3))) void*)(lds + (ldsoff_) + wid * 1024), 16, 0, 0);\
    __builtin_amdgcn_global_load_lds(                                                      \
        (const __attribute__((address_space(1))) void*)((gbase_) + eo1),                   \
        (__attribute__((address_space(3))) void*)(lds + (ldsoff_) + 8192 + wid * 1024),    \
        16, 0, 0);                                                                         \
  } while (0)

  // frag read base byte offsets within a 16KB half (swizzle matches staging)
  const int a_ks0 = lo * 128 + (((0 + hi) ^ (lo & 7)) << 4);
  const int a_ks1 = lo * 128 + (((4 + hi) ^ (lo & 7)) << 4);
  const int bfrag_base = (wn & 1) * 8192;  // (wn&1)*64 rows * 128B

  f32x4 acc[8][4];
#pragma unroll
  for (int i = 0; i < 8; ++i)
#pragma unroll
    for (int j = 0; j < 4; ++j) acc[i][j] = (f32x4){0.f, 0.f, 0.f, 0.f};

  short8 af[8][2], bfr[2][2];

  auto loadA = [&](const char* Ah) {
#pragma unroll
    for (int fm = 0; fm < 8; ++fm) {
      af[fm][0] = *(const short8*)(Ah + a_ks0 + fm * 2048);
      af[fm][1] = *(const short8*)(Ah + a_ks1 + fm * 2048);
    }
  };
  auto loadB = [&](const char* Bh, int f0) {
#pragma unroll
    for (int j = 0; j < 2; ++j) {
      bfr[j][0] = *(const short8*)(Bh + a_ks0 + (f0 + j) * 2048);
      bfr[j][1] = *(const short8*)(Bh + a_ks1 + (f0 + j) * 2048);
    }
  };
  auto quad = [&](int FM0, int FN0) {
    __builtin_amdgcn_s_setprio(1);
#pragma unroll
    for (int fm = 0; fm < 4; ++fm)
#pragma unroll
      for (int j = 0; j < 2; ++j) {
        acc[FM0 + fm][FN0 + j] = __builtin_amdgcn_mfma_f32_16x16x32_bf16(
            af[FM0 + fm][0], bfr[j][0], acc[FM0 + fm][FN0 + j], 0, 0, 0);
        acc[FM0 + fm][FN0 + j] = __builtin_amdgcn_mfma_f32_16x16x32_bf16(
            af[FM0 + fm][1], bfr[j][1], acc[FM0 + fm][FN0 + j], 0, 0, 0);
      }
    __builtin_amdgcn_s_setprio(0);
  };

  const int nkt = K >> 6;  // >= 3 always here (16 or 32)

  // prologue: tile0 (4 halves) + tile1 (A0,A1,B0) = 7 halves
  STAGE(Abase, ALDS(0, 0));
  STAGE(Abase + khalf, ALDS(0, 1));
  STAGE(Bbase, BLDS(0, 0));
  STAGE(Bbase + khalf, BLDS(0, 1));
  STAGE(Abase + 64, ALDS(1, 0));
  STAGE(Abase + khalf + 64, ALDS(1, 1));
  STAGE(Bbase + 64, BLDS(1, 0));
  WAIT_VM(6);  // tile0's 8 loads landed; tile1's 6 in flight
  BAR();

  for (int t = 0; t < nkt; ++t) {
    const int buf = t & 1;
    const char* Ah = lds + ALDS(buf, wm);
    const char* Bh = lds + BLDS(buf, wn >> 1) + bfrag_base;

    // ---- q0: all A frags + B lo; stage B1(t+1) ----
    loadA(Ah);
    loadB(Bh, 0);
    if (t + 1 < nkt) STAGE(Bbase + khalf + (size_t)(t + 1) * 64, BLDS((t + 1) & 1, 1));
    BAR();
    WAIT_LGKM0();  // all A reads drained -> A halves restageable after next barrier
    quad(0, 0);
    BAR();

    // ---- q1: stage A0(t+2) ----
    if (t + 2 < nkt) STAGE(Abase + (size_t)(t + 2) * 64, ALDS(buf, 0));
    BAR();
    quad(4, 0);
    BAR();

    // ---- q2: B hi; stage A1(t+2) ----
    loadB(Bh, 2);
    if (t + 2 < nkt) STAGE(Abase + khalf + (size_t)(t + 2) * 64, ALDS(buf, 1));
    BAR();
    WAIT_LGKM0();  // B reads drained -> B halves restageable after next barrier
    quad(0, 2);
    BAR();

    // ---- q3: stage B0(t+2) ----
    if (t + 2 < nkt) STAGE(Bbase + (size_t)(t + 2) * 64, BLDS(buf, 0));
    BAR();
    quad(4, 2);
    // tile boundary: ensure tile t+1 fully landed; allow 3 newest halves in flight
    if (t + 2 < nkt) {
      WAIT_VM(6);
    } else {
      WAIT_VM(0);
    }
    BAR();
  }

  // epilogue: C/D layout col=lane&15, row=(lane>>4)*4+reg
  const int row0 = m0 + wm * 128 + hi * 4;
  const int col0 = n0 + wn * 64 + lo;
#pragma unroll
  for (int fm = 0; fm < 8; ++fm)
#pragma unroll
    for (int fn = 0; fn < 4; ++fn)
#pragma unroll
      for (int r = 0; r < 4; ++r) {
        float v = acc[fm][fn][r];
        if (RELU) v = fmaxf(v, 0.f);
        Ce[(size_t)(row0 + fm * 16 + r) * Nm + (col0 + fn * 16)] = f2bf(v);
      }
#undef STAGE
}

// ---------------- gather: out[e,dst,:] = sum over in-edges of y[e,src,:] ----------------

__global__ __launch_bounds__(256) void gather_sum(
    const unsigned short* __restrict__ y, const int* __restrict__ rowptr,
    const int* __restrict__ csr, float* __restrict__ out) {
  const int dst = blockIdx.x;
  const int e = blockIdx.y;
  const unsigned short* ye = y + (size_t)e * N_ * D_;
  float* oute = out + (size_t)e * N_ * D_ + (size_t)dst * D_;
  const int t = threadIdx.x;  // 256 threads x 4 elems = 1024 = D
  const int beg = rowptr[dst], end = rowptr[dst + 1];
  float a0 = 0.f, a1 = 0.f, a2 = 0.f, a3 = 0.f;
  for (int i = beg; i < end; ++i) {
    const int s = csr[i];
    ushort4 v = ((const ushort4*)(ye + (size_t)s * D_))[t];
    a0 += bf2f(v.x);
    a1 += bf2f(v.y);
    a2 += bf2f(v.z);
    a3 += bf2f(v.w);
  }
  float4 o;
  o.x = a0; o.y = a1; o.z = a2; o.w = a3;
  ((float4*)oute)[t] = o;
}

// ---------------- launch ----------------

extern "C" void kernel_launch(void* const* d_in, const int* in_sizes, int n_in,
                              void* d_out, int out_size, void* d_ws, size_t ws_size,
                              hipStream_t stream) {
  (void)in_sizes; (void)n_in; (void)out_size; (void)ws_size;
  const float* x = (const float*)d_in[0];
  const float* W1 = (const float*)d_in[1];
  const float* W2 = (const float*)d_in[2];
  const int* ei = (const int*)d_in[3];
  float* out = (float*)d_out;

  char* p = (char*)d_ws;
  auto alloc = [&](size_t b) {
    char* r = p;
    p += (b + 255) & ~(size_t)255;
    return r;
  };
  unsigned short* xbf = (unsigned short*)alloc((size_t)E_ * N_ * D_ * 2);    // 64 MiB
  unsigned short* w1t = (unsigned short*)alloc((size_t)E_ * D_ * DFF_ * 2);  // 32 MiB
  unsigned short* w2t = (unsigned short*)alloc((size_t)E_ * DFF_ * D_ * 2);  // 32 MiB
  unsigned short* h = (unsigned short*)alloc((size_t)E_ * N_ * DFF_ * 2);    // 128 MiB
  unsigned short* y = (unsigned short*)alloc((size_t)E_ * N_ * D_ * 2);      // 64 MiB
  int* cnt = (int*)alloc((size_t)N_ * 4);
  int* rowptr = (int*)alloc((size_t)(N_ + 1) * 4);
  int* cursor = (int*)alloc((size_t)N_ * 4);
  int* csr = (int*)alloc((size_t)NE_ * 4);

  // input conversion
  cvt_f32_bf16_vec<<<(E_ * N_ * D_ / 4 + 255) / 256, 256, 0, stream>>>(x, xbf, E_ * N_ * D_ / 4);
  transpose_cvt<<<dim3(DFF_ / 32, D_ / 32, E_), 256, 0, stream>>>(W1, w1t, D_, DFF_);
  transpose_cvt<<<dim3(D_ / 32, DFF_ / 32, E_), 256, 0, stream>>>(W2, w2t, DFF_, D_);

  // CSR build (edge graph shared across experts)
  zero_i32<<<(N_ + 255) / 256, 256, 0, stream>>>(cnt, N_);
  hist_dst<<<NE_ / 256, 256, 0, stream>>>(ei, cnt, NE_);
  scan4096<<<1, 1024, 0, stream>>>(cnt, rowptr, cursor);
  fill_csr<<<NE_ / 256, 256, 0, stream>>>(ei, cursor, csr, NE_);

  // h = relu(x @ W1)   [E][N][DFF] bf16
  {
    int nbx = DFF_ / 256, nby = N_ / 256;
    gemm256<true><<<nbx * nby * E_, 512, 0, stream>>>(xbf, w1t, h, N_, DFF_, D_, nbx, nbx * nby);
  }
  // y = h @ W2         [E][N][D] bf16
  {
    int nbx = D_ / 256, nby = N_ / 256;
    gemm256<false><<<nbx * nby * E_, 512, 0, stream>>>(h, w2t, y, N_, D_, DFF_, nbx, nbx * nby);
  }

  // out = A @ y  (CSR gather, f32 accumulate)
  gather_sum<<<dim3(N_, E_), 256, 0, stream>>>(y, rowptr, csr, out);
}